// Round 3
// baseline (16193.489 us; speedup 1.0000x reference)
//
#include <hip/hip_runtime.h>

// shallowPLRNN on MI355X — round 5: single-barrier partial-sum decomposition.
// Repartition: each of 4 blocks per subject owns W2 rows [256j,256j+256) AND
// W1 columns [256j,256j+256). Hidden = relu(W2_j z + h2_j) is produced and
// consumed inside the block (LDS only). The only cross-block exchange is the
// partial sum P_j = W1[:,cols_j] @ hid_j (full 256-dim z partial). Each block
// reads all 4 partials and redundantly reconstructs full z in LDS/registers.
//   - ONE group barrier per step (was two)
//   - zero global round-trips for hidden and z-state (was two)
//   - P double-buffered by step parity (prevents overwrite-while-read race)
//   - decode placed between P-store and barrier (hides in drain/skew window)
// Barrier mechanism identical to proven round-4 light/heavy scheme (4-wide).

typedef _Float16 f16;
typedef _Float16 f16x8 __attribute__((ext_vector_type(8)));
typedef float f32x4 __attribute__((ext_vector_type(4)));

#define TSTEPS 1024

// ---- workspace byte offsets (total ~6.02 MB) ----
#define WS_C     0ul          // C table: 64x64 fp32
#define WS_P     16384ul      // P partials: 2(par) x 16(s) x 4(j) x 48 x 256 fp32
#define WS_ORDER 6307840ul    // sample order (256 int)
#define WS_CNT   6308864ul    // per-subject count (16 int)
#define WS_OFFS  6308928ul    // per-subject offset (16 int)
#define WS_CTR   6308992ul    // barrier counters (16 x 128B; [0]=loop, [16]=handshake)
#define WS_XCC   6311040ul    // per-group XCC ids (16 x 4 int)
#define WS_NEED  6311296ul

// ---- main-kernel static LDS layout (bytes, total 60864 <= 64KB) ----
#define SM_ZPK   0            // zpk:  [48][280] f16 (post-TF z, full 256 dims)
#define SM_ZPRE  26880        // zpre: [48][72]  f16 (pre-TF z, d<64, for decode)
#define SM_TBUF  33792        // tbuf: [48][280] f16 (block-local hidden slice, K=256)
#define SM_ORD   60672        // ordl: [48] int
#define SM_SIZE  60864

// 4-block per-subject barrier; monotonic counter, agent scope.
// heavy (light=false): full agent release/acquire fences — correct cross-XCD.
// light (light=true) : same-XCD only. Stores are already in the shared XCD L2
// (write-through L1 + vmcnt drain at __syncthreads); acquire side only needs
// the CU's vector L1 invalidated so post-barrier loads refill from L2.
__device__ __forceinline__ void group_barrier(int* ctr, int target, bool light) {
    __syncthreads();
    if (threadIdx.x == 0) {
        if (!light)
            __builtin_amdgcn_fence(__ATOMIC_RELEASE, "agent");   // buffer_wbl2 sc1
        __hip_atomic_fetch_add(ctr, 1, __ATOMIC_RELAXED, __HIP_MEMORY_SCOPE_AGENT);
        while (__hip_atomic_load(ctr, __ATOMIC_RELAXED, __HIP_MEMORY_SCOPE_AGENT) < target)
            __builtin_amdgcn_s_sleep(1);
        if (!light)
            __builtin_amdgcn_fence(__ATOMIC_ACQUIRE, "agent");   // buffer_inv sc1
        else
            asm volatile("buffer_inv" ::: "memory");             // L1-only invalidate
    }
    __syncthreads();
}

// ---------- prep: C = (M^T M)^-1 M[:64,:]^T  (64x64), fp32 Gauss-Jordan ----------
__global__ __launch_bounds__(256) void prep_kernel(const float* __restrict__ M,
                                                   float* __restrict__ C) {
    __shared__ float aug[64 * 132];
    __shared__ float fac[64];
    int tid = threadIdx.x;
    {
        int i = tid >> 2;
        int j0 = (tid & 3) * 16;
        float acc[16];
        #pragma unroll
        for (int e = 0; e < 16; ++e) acc[e] = 0.f;
        for (int r = 0; r < 256; ++r) {
            float mi = M[r*64 + i];
            #pragma unroll
            for (int e = 0; e < 16; ++e) acc[e] += mi * M[r*64 + j0 + e];
        }
        #pragma unroll
        for (int e = 0; e < 16; ++e) aug[i*132 + j0 + e] = acc[e];
    }
    for (int idx = tid; idx < 4096; idx += 256) {
        int x = idx >> 6, c = idx & 63;
        aug[x*132 + 64 + c] = M[c*64 + x];
    }
    __syncthreads();
    for (int p = 0; p < 64; ++p) {
        float piv = aug[p*132 + p];
        __syncthreads();
        if (tid < 128) aug[p*132 + tid] /= piv;
        __syncthreads();
        if (tid < 64) fac[tid] = aug[tid*132 + p];
        __syncthreads();
        for (int idx = tid; idx < 8192; idx += 256) {
            int r = idx >> 7, c = idx & 127;
            if (r != p) aug[r*132 + c] -= fac[r] * aug[p*132 + c];
        }
        __syncthreads();
    }
    for (int idx = tid; idx < 4096; idx += 256) {
        int x = idx >> 6, c = idx & 63;
        C[x*64 + c] = aug[x*132 + 64 + c];
    }
}

// ---------- forcing: out[b][t][0:64] = x[b][t][:] @ C   (fp32, into d_out!) ----------
__global__ __launch_bounds__(256) void forcing_kernel(const float* __restrict__ x,
        const float* __restrict__ C, float* __restrict__ fout) {
    __shared__ float xs[64 * 68];
    __shared__ float Cs[64 * 64];
    int tid = threadIdx.x;
    for (int i = tid; i < 1024; i += 256)
        ((float4*)Cs)[i] = ((const float4*)C)[i];
    long r0 = (long)blockIdx.x * 64;
    int b  = (int)(r0 >> 10);
    int t0 = (int)(r0 & 1023);
    const float4* xb = (const float4*)(x + ((long)b * 1024 + t0) * 64);
    for (int i = tid; i < 1024; i += 256) {
        float4 v = xb[i];
        int row = i >> 4, col = (i & 15) * 4;
        *(float4*)&xs[row*68 + col] = v;
    }
    __syncthreads();
    int row = tid >> 2, cg = (tid & 3) * 16;
    float acc[16];
    #pragma unroll
    for (int e = 0; e < 16; ++e) acc[e] = 0.f;
    for (int k = 0; k < 64; ++k) {
        float xv = xs[row*68 + k];
        const float* cr = &Cs[k*64 + cg];
        #pragma unroll
        for (int e = 0; e < 16; ++e) acc[e] += xv * cr[e];
    }
    float4* dst = (float4*)(fout + ((size_t)b*1024 + t0 + row)*64 + cg);
    #pragma unroll
    for (int e = 0; e < 4; ++e) {
        float4 v; v.x = acc[4*e]; v.y = acc[4*e+1]; v.z = acc[4*e+2]; v.w = acc[4*e+3];
        dst[e] = v;
    }
}

// ---------- grouping: bucket samples by subject, zero barrier counters ----------
__global__ __launch_bounds__(256) void group_kernel(const int* __restrict__ subject,
        int* order, int* cnt, int* offs, int* ctr) {
    __shared__ int lc[16], lo[16], cur[16];
    int tid = threadIdx.x;
    if (tid < 16) { lc[tid] = 0; cur[tid] = 0; }
    __syncthreads();
    int s = subject[tid];
    atomicAdd(&lc[s], 1);
    __syncthreads();
    if (tid == 0) { int a = 0; for (int i = 0; i < 16; ++i) { lo[i] = a; a += lc[i]; } }
    __syncthreads();
    int pos = lo[s] + atomicAdd(&cur[s], 1);
    order[pos] = tid;
    if (tid < 16) {
        cnt[tid] = lc[tid]; offs[tid] = lo[tid];
        ctr[tid*32] = 0;        // main loop counter
        ctr[tid*32 + 16] = 0;   // XCC handshake counter
    }
}

// ---------- main persistent kernel (64 blocks, 4 per subject) ----------
template<int NT>
__device__ __forceinline__ void run_group(int s, int j, int Bs, int off,
    const float* __restrict__ W1t, const float* __restrict__ W2t,
    const float* __restrict__ At,  const float* __restrict__ h1t,
    const float* __restrict__ h2t, const float* __restrict__ Mt,
    float* __restrict__ Pbuf, const int* __restrict__ order,
    int* ctr, float* out, char* sm, bool light)
{
    f16*   zpk  = (f16*)(sm + SM_ZPK);      // [48][280] post-TF z (raw for d>=64)
    f16*   zpre = (f16*)(sm + SM_ZPRE);     // [48][72]  raw z, d<64 (decode)
    f16*   tbuf = (f16*)(sm + SM_TBUF);     // [48][280] block-local hidden
    int*   ordl = (int*)(sm + SM_ORD);

    const int tid  = threadIdx.x;
    const int w    = tid >> 6;
    const int lane = tid & 63;
    const int q    = lane >> 4;
    const int li   = lane & 15;
    const int d    = tid;                   // reduce-owned z dim (0..255)

    if (tid < 48) ordl[tid] = (tid < Bs) ? order[off + tid] : 0;
    __syncthreads();

    const float an  = At [s*256 + d];       // A[d], h1[d] — 2 VGPRs only
    const float h1n = h1t[s*256 + d];

    // ---- preload weight fragments into VGPRs (held across all T steps) ----
    // W2 rows [256j,256j+256), K = full z (256): wave w owns rows 64w..64w+64
    // W1 rows = all 256 z-dims (wave w owns 64), K = hid cols [256j,256j+256)
    f16x8 w2f[4][8], w1f[4][8], mfr[8];
    float h2v[4][4];
    const f32x4 zero4 = {0.f, 0.f, 0.f, 0.f};
    #pragma unroll
    for (int m = 0; m < 4; ++m) {
        const float* src = W2t + (size_t)s*262144 + (size_t)(256*j + 64*w + 16*m + li)*256;
        #pragma unroll
        for (int kt = 0; kt < 8; ++kt) {
            int k0 = kt*32 + q*8;
            #pragma unroll
            for (int e = 0; e < 8; ++e) w2f[m][kt][e] = (f16)src[k0+e];
        }
    }
    #pragma unroll
    for (int m = 0; m < 4; ++m) {
        const float* src = W1t + (size_t)s*262144 + (size_t)(64*w + 16*m + li)*1024 + 256*j;
        #pragma unroll
        for (int kt = 0; kt < 8; ++kt) {
            int k0 = kt*32 + q*8;
            #pragma unroll
            for (int e = 0; e < 8; ++e) w1f[m][kt][e] = (f16)src[k0+e];
        }
    }
    #pragma unroll
    for (int kt = 0; kt < 8; ++kt)   // obs_matrix B-frags; wave w owns dx cols [16w,16w+16)
        #pragma unroll
        for (int e = 0; e < 8; ++e)
            mfr[kt][e] = (f16)Mt[(kt*32 + q*8 + e)*64 + 16*w + li];
    #pragma unroll
    for (int m = 0; m < 4; ++m)
        #pragma unroll
        for (int r = 0; r < 4; ++r)
            h2v[m][r] = h2t[s*1024 + 256*j + 64*w + 16*m + q*4 + r];

    // ---- init: z0[d<64] = forcing[:,0,:64]; TF(f0,f0)=f0 so zpk=z0 ----
    float azh[NT*16];                       // A*z_tf + h1 carried across barrier
    #pragma unroll
    for (int n = 0; n < NT*16; ++n) {
        float z0 = 0.f;
        if (d < 64 && n < Bs) z0 = out[(size_t)ordl[n]*65536 + d];
        zpk[n*280 + d] = (f16)z0;
        if (d < 64) zpre[n*72 + d] = (f16)z0;
        azh[n] = an*z0 + h1n;
    }
    __syncthreads();

    int gen = 0;
    for (int t = 0; t < TSTEPS; ++t) {
        // ---- phase A: hid_j = relu(W2_j @ z_tf + h2_j) -> tbuf (LDS only) ----
        #pragma unroll
        for (int nt = 0; nt < NT; ++nt) {
            f32x4 acc[4] = {zero4, zero4, zero4, zero4};
            #pragma unroll
            for (int kt = 0; kt < 8; ++kt) {
                f16x8 bf = *(const f16x8*)&zpk[(16*nt + li)*280 + kt*32 + q*8];
                #pragma unroll
                for (int m = 0; m < 4; ++m)
                    acc[m] = __builtin_amdgcn_mfma_f32_16x16x32_f16(w2f[m][kt], bf, acc[m], 0,0,0);
            }
            #pragma unroll
            for (int m = 0; m < 4; ++m)
                #pragma unroll
                for (int r = 0; r < 4; ++r) {
                    float hv = acc[m][r] + h2v[m][r];
                    hv = hv > 0.f ? hv : 0.f;
                    tbuf[(16*nt + li)*280 + 64*w + 16*m + 4*q + r] = (f16)hv;
                }
        }
        __syncthreads();

        // ---- phase B: P_j = W1[:,cols_j] @ hid_j -> global partial (fp32) ----
        float* Pmy = Pbuf + (size_t)(((t & 1)*16 + s)*4 + j)*12288;
        #pragma unroll
        for (int nt = 0; nt < NT; ++nt) {
            f32x4 bacc[4] = {zero4, zero4, zero4, zero4};
            #pragma unroll
            for (int kt = 0; kt < 8; ++kt) {
                f16x8 bf = *(const f16x8*)&tbuf[(16*nt + li)*280 + kt*32 + q*8];
                #pragma unroll
                for (int m = 0; m < 4; ++m)
                    bacc[m] = __builtin_amdgcn_mfma_f32_16x16x32_f16(w1f[m][kt], bf, bacc[m], 0,0,0);
            }
            #pragma unroll
            for (int m = 0; m < 4; ++m)
                *(f32x4*)&Pmy[(16*nt + li)*256 + 64*w + 16*m + 4*q] = bacc[m];
        }

        // ---- decode out[b][t-1] = z_t @ M (overlaps P-store drain + skew) ----
        if (t > 0 && j < NT) {
            f32x4 dacc = zero4;
            #pragma unroll
            for (int kt = 0; kt < 8; ++kt) {
                f16x8 af;
                if (kt < 2) af = *(const f16x8*)&zpre[(16*j + li)*72 + kt*32 + q*8];
                else        af = *(const f16x8*)&zpk [(16*j + li)*280 + kt*32 + q*8];
                dacc = __builtin_amdgcn_mfma_f32_16x16x32_f16(af, mfr[kt], dacc, 0, 0, 0);
            }
            #pragma unroll
            for (int r = 0; r < 4; ++r) {
                int n = 16*j + q*4 + r;
                if (n < Bs)
                    out[((size_t)ordl[n]*TSTEPS + (t-1))*64 + 16*w + li] = dacc[r];
            }
        }

        ++gen;
        group_barrier(ctr, 4*gen, light);   // the ONLY group barrier per step

        // ---- reduce: z' = azh + sum_j P_j; TF; rebuild zpk/zpre/azh ----
        {
            const float* Pb = Pbuf + (size_t)(((t & 1)*16 + s)*4)*12288;
            const float* P0 = Pb;
            const float* P1 = Pb + 12288;
            const float* P2 = Pb + 24576;
            const float* P3 = Pb + 36864;
            #pragma unroll
            for (int n = 0; n < NT*16; ++n) {
                int o = n*256 + d;
                float sum = (P0[o] + P1[o]) + (P2[o] + P3[o]);
                float zr = azh[n] + sum;
                float zh = zr;
                if (d < 64) {
                    zpre[n*72 + d] = (f16)zr;
                    if (t+1 < TSTEPS && n < Bs) {
                        float fv = out[(size_t)ordl[n]*65536 + (size_t)(t+1)*64 + d];
                        zh = 0.2f*fv + 0.8f*zr;
                    }
                }
                zpk[n*280 + d] = (f16)zh;
                azh[n] = an*zh + h1n;
            }
        }
        __syncthreads();
    }

    // ---- final decode: out[b][T-1] = z_T @ M ----
    if (j < NT) {
        f32x4 dacc = zero4;
        #pragma unroll
        for (int kt = 0; kt < 8; ++kt) {
            f16x8 af;
            if (kt < 2) af = *(const f16x8*)&zpre[(16*j + li)*72 + kt*32 + q*8];
            else        af = *(const f16x8*)&zpk [(16*j + li)*280 + kt*32 + q*8];
            dacc = __builtin_amdgcn_mfma_f32_16x16x32_f16(af, mfr[kt], dacc, 0, 0, 0);
        }
        #pragma unroll
        for (int r = 0; r < 4; ++r) {
            int n = 16*j + q*4 + r;
            if (n < Bs)
                out[((size_t)ordl[n]*TSTEPS + (TSTEPS-1))*64 + 16*w + li] = dacc[r];
        }
    }
}

__global__ __launch_bounds__(256, 1) void main_kernel(
    const float* W1t, const float* W2t, const float* At, const float* h1t,
    const float* h2t, const float* Mt, float* Pbuf,
    const int* order, const int* cnt, const int* offs, int* ctr, int* xccg,
    float* out)
{
    __shared__ __align__(16) char sm[SM_SIZE];
    int bid = blockIdx.x;
    int s = bid & 15;          // bid = s + 16j: all 4 blocks share bid%8 (XCD affinity)
    int j = bid >> 4;
    int Bs = cnt[s];
    if (Bs <= 0) return;       // whole group exits consistently
    if (Bs > 48) Bs = 48;
    int off = offs[s];
    int* myctr = ctr + s*32;

    // ---- one-shot XCD handshake: decide light vs heavy barriers ----
    int xcc;
    asm volatile("s_getreg_b32 %0, hwreg(HW_REG_XCC_ID)" : "=s"(xcc));
    xcc &= 0xf;
    if (threadIdx.x == 0) xccg[s*4 + j] = xcc;
    group_barrier(myctr + 16, 4, false);   // heavy: publishes xcc cross-XCD
    bool light = true;
    #pragma unroll
    for (int i = 0; i < 4; ++i) light = light && (xccg[s*4 + i] == xcc);

    int NT = (Bs + 15) >> 4;
    if (NT == 1)
        run_group<1>(s, j, Bs, off, W1t, W2t, At, h1t, h2t, Mt, Pbuf, order, myctr, out, sm, light);
    else if (NT == 2)
        run_group<2>(s, j, Bs, off, W1t, W2t, At, h1t, h2t, Mt, Pbuf, order, myctr, out, sm, light);
    else
        run_group<3>(s, j, Bs, off, W1t, W2t, At, h1t, h2t, Mt, Pbuf, order, myctr, out, sm, light);
}

extern "C" void kernel_launch(void* const* d_in, const int* in_sizes, int n_in,
                              void* d_out, int out_size, void* d_ws, size_t ws_size,
                              hipStream_t stream) {
    const float* x    = (const float*)d_in[0];
    const int*   subj = (const int*)d_in[1];
    const float* Mt   = (const float*)d_in[2];
    const float* At   = (const float*)d_in[3];
    const float* W1t  = (const float*)d_in[4];
    const float* W2t  = (const float*)d_in[5];
    const float* h1t  = (const float*)d_in[6];
    const float* h2t  = (const float*)d_in[7];
    float* out = (float*)d_out;
    char*  ws  = (char*)d_ws;
    if (ws_size < WS_NEED) return;  // fail-soft (need ~6.02 MB)

    float* C     = (float*)(ws + WS_C);
    float* Pbuf  = (float*)(ws + WS_P);
    int*   order = (int*)(ws + WS_ORDER);
    int*   cnt   = (int*)(ws + WS_CNT);
    int*   offs  = (int*)(ws + WS_OFFS);
    int*   ctr   = (int*)(ws + WS_CTR);
    int*   xccg  = (int*)(ws + WS_XCC);

    prep_kernel<<<1, 256, 0, stream>>>(Mt, C);
    forcing_kernel<<<4096, 256, 0, stream>>>(x, C, out);
    group_kernel<<<1, 256, 0, stream>>>(subj, order, cnt, offs, ctr);
    main_kernel<<<64, 256, 0, stream>>>(W1t, W2t, At, h1t, h2t, Mt,
                                        Pbuf, order, cnt, offs, ctr, xccg, out);
}